// Round 1
// baseline (2051.400 us; speedup 1.0000x reference)
//
#include <hip/hip_runtime.h>

// Problem constants
#define N_ROWS   32768
#define K_DIM    2304
#define MG       2816     // W cols = SIZE_OUT + NUM_GATES
#define SIZE_OUT 2304
#define NGATE    512

// Tile geometry
#define BM 128
#define BN 128
#define BK 32
#define LDSK 40           // padded LDS row stride in shorts (80 B)

typedef short bf16x8 __attribute__((ext_vector_type(8)));
typedef short s16x4  __attribute__((ext_vector_type(4)));
typedef float f32x4  __attribute__((ext_vector_type(4)));

__device__ __forceinline__ short f2bf(float f) {
    unsigned u = __builtin_bit_cast(unsigned, f);
    unsigned r = u + 0x7FFFu + ((u >> 16) & 1u);   // RNE to bf16
    return (short)(r >> 16);
}
__device__ __forceinline__ float bf2f(short s) {
    unsigned u = ((unsigned)(unsigned short)s) << 16;
    return __builtin_bit_cast(float, u);
}

// ---------------------------------------------------------------------------
// Pre-kernel: split W (fp32, [K][MG] row-major) into hi/lo bf16, transposed
// to [MG][K] so GEMM B-staging reads contiguous k per output column.
// ---------------------------------------------------------------------------
__global__ __launch_bounds__(256)
void split_w_k(const float* __restrict__ W, short* __restrict__ wh,
               short* __restrict__ wl) {
    const int kc = blockIdx.x;                       // k-chunk of 8
    const int m  = blockIdx.y * 256 + threadIdx.x;   // output column
    bf16x8 h, l;
#pragma unroll
    for (int j = 0; j < 8; ++j) {
        float f = W[(size_t)(kc * 8 + j) * MG + m];  // coalesced across block
        short hb = f2bf(f);
        h[j] = hb;
        l[j] = f2bf(f - bf2f(hb));                   // exact residual, rounded
    }
    *(bf16x8*)&wh[(size_t)m * K_DIM + kc * 8] = h;
    *(bf16x8*)&wl[(size_t)m * K_DIM + kc * 8] = l;
}

// ---------------------------------------------------------------------------
// Split-bf16 MFMA GEMM. MODE 0: gate cols (W cols 2304:2816) -> sigmoid -> ws.
// MODE 1: field cols (0:2304) -> silu / gate-mul epilogue -> out.
// 128x128 tile, BK=32, 4 waves (2x2), each wave 64x64 = 4x4 frags of 16x16.
// ---------------------------------------------------------------------------
template <int MODE>
__global__ __launch_bounds__(256, 2)
void gemm_k(const float* __restrict__ x, const short* __restrict__ wh,
            const short* __restrict__ wl, float* __restrict__ gates,
            float* __restrict__ out) {
    __shared__ short Ah[BM * LDSK], Al[BM * LDSK];
    __shared__ short Bh[BN * LDSK], Bl[BN * LDSK];

    const int tid  = threadIdx.x;
    const int lane = tid & 63;
    const int wave = tid >> 6;
    const int wm = wave >> 1, wn = wave & 1;
    const int n0 = blockIdx.x * BN;                  // local col base
    const int r0 = blockIdx.y * BM;                  // row base
    const int wcol0 = (MODE == 0 ? SIZE_OUT : 0) + n0;  // row index into wh/wl

    // staging assignment: 2 threads per row, 16 elems each
    const int srow = tid >> 1;            // 0..127
    const int skh  = (tid & 1) * 16;      // element offset 0/16

    const float* xp  = x  + (size_t)(r0 + srow) * K_DIM + skh;
    const short* whp = wh + (size_t)(wcol0 + srow) * K_DIM + skh;
    const short* wlp = wl + (size_t)(wcol0 + srow) * K_DIM + skh;

    f32x4 acc[4][4] = {};

    const int frow = lane & 15;
    const int fk   = (lane >> 4) * 8;

    for (int kt = 0; kt < K_DIM / BK; ++kt) {
        const float* ap  = xp  + kt * BK;
        const short* bhp = whp + kt * BK;
        const short* blp = wlp + kt * BK;

        // issue global loads before barrier: latency overlaps prev MFMA
        s16x4 ah_[4], al_[4];
#pragma unroll
        for (int c = 0; c < 4; ++c) {
            f32x4 v = *(const f32x4*)(ap + c * 4);
#pragma unroll
            for (int e = 0; e < 4; ++e) {
                short hb = f2bf(v[e]);
                ah_[c][e] = hb;
                al_[c][e] = f2bf(v[e] - bf2f(hb));
            }
        }
        bf16x8 bh0 = *(const bf16x8*)(bhp);
        bf16x8 bh1 = *(const bf16x8*)(bhp + 8);
        bf16x8 bl0 = *(const bf16x8*)(blp);
        bf16x8 bl1 = *(const bf16x8*)(blp + 8);

        __syncthreads();   // prev iteration's frag reads complete
#pragma unroll
        for (int c = 0; c < 4; ++c) {
            *(s16x4*)&Ah[srow * LDSK + skh + c * 4] = ah_[c];
            *(s16x4*)&Al[srow * LDSK + skh + c * 4] = al_[c];
        }
        *(bf16x8*)&Bh[srow * LDSK + skh]     = bh0;
        *(bf16x8*)&Bh[srow * LDSK + skh + 8] = bh1;
        *(bf16x8*)&Bl[srow * LDSK + skh]     = bl0;
        *(bf16x8*)&Bl[srow * LDSK + skh + 8] = bl1;
        __syncthreads();

        bf16x8 a_h[4], a_l[4], b_h[4], b_l[4];
#pragma unroll
        for (int i = 0; i < 4; ++i) {
            const int ar = (wm * 64 + i * 16 + frow) * LDSK + fk;
            a_h[i] = *(const bf16x8*)&Ah[ar];
            a_l[i] = *(const bf16x8*)&Al[ar];
            const int br = (wn * 64 + i * 16 + frow) * LDSK + fk;
            b_h[i] = *(const bf16x8*)&Bh[br];
            b_l[i] = *(const bf16x8*)&Bl[br];
        }
#pragma unroll
        for (int i = 0; i < 4; ++i)
#pragma unroll
            for (int j = 0; j < 4; ++j) {
                acc[i][j] = __builtin_amdgcn_mfma_f32_16x16x32_bf16(
                    a_h[i], b_h[j], acc[i][j], 0, 0, 0);
                acc[i][j] = __builtin_amdgcn_mfma_f32_16x16x32_bf16(
                    a_h[i], b_l[j], acc[i][j], 0, 0, 0);
                acc[i][j] = __builtin_amdgcn_mfma_f32_16x16x32_bf16(
                    a_l[i], b_h[j], acc[i][j], 0, 0, 0);
            }
    }

    // Epilogue. D layout: col = lane&15, row = (lane>>4)*4 + reg.
    const int rb = r0 + wm * 64 + ((lane >> 4) << 2);
    const int cb = n0 + wn * 64 + (lane & 15);

    if (MODE == 0) {
#pragma unroll
        for (int i = 0; i < 4; ++i)
#pragma unroll
            for (int j = 0; j < 4; ++j) {
                const int c = cb + j * 16;
#pragma unroll
                for (int r = 0; r < 4; ++r) {
                    const int row = rb + i * 16 + r;
                    float v = acc[i][j][r];
                    gates[(size_t)row * NGATE + c] = 1.0f / (1.0f + __expf(-v));
                }
            }
    } else {
#pragma unroll
        for (int i = 0; i < 4; ++i)
#pragma unroll
            for (int j = 0; j < 4; ++j) {
                const int c = cb + j * 16;
                int g = 0;
                if (n0 >= 256) g = (n0 < 1024) ? (c - 256) / 3
                                               : 256 + (c - 1024) / 5;
#pragma unroll
                for (int r = 0; r < 4; ++r) {
                    const int row = rb + i * 16 + r;
                    float v = acc[i][j][r];
                    float o;
                    if (n0 < 256) {
                        o = v / (1.0f + __expf(-v));             // silu
                    } else {
                        o = v * gates[(size_t)row * NGATE + g];  // gated
                    }
                    out[(size_t)row * SIZE_OUT + c] = o;
                }
            }
    }
}

// ---------------------------------------------------------------------------
extern "C" void kernel_launch(void* const* d_in, const int* in_sizes, int n_in,
                              void* d_out, int out_size, void* d_ws,
                              size_t ws_size, hipStream_t stream) {
    const float* x = (const float*)d_in[0];
    const float* W = (const float*)d_in[1];
    float* out = (float*)d_out;

    char* ws = (char*)d_ws;
    const size_t wbytes = (size_t)MG * K_DIM * 2;         // one bf16 plane
    short* wh    = (short*)ws;
    short* wl    = (short*)(ws + wbytes);
    float* gates = (float*)(ws + 2 * wbytes);
    const size_t needed = 2 * wbytes + (size_t)N_ROWS * NGATE * 4;  // ~93 MB
    if (ws_size < needed) return;  // fail loudly (output stays poisoned)

    split_w_k<<<dim3(K_DIM / 8, MG / 256), 256, 0, stream>>>(W, wh, wl);
    gemm_k<0><<<dim3(NGATE / BN, N_ROWS / BM), 256, 0, stream>>>(x, wh, wl,
                                                                 gates, out);
    gemm_k<1><<<dim3(SIZE_OUT / BN, N_ROWS / BM), 256, 0, stream>>>(x, wh, wl,
                                                                    gates, out);
}

// Round 2
// 1754.352 us; speedup vs baseline: 1.1693x; 1.1693x over previous
//
#include <hip/hip_runtime.h>

// Problem constants
#define N_ROWS   32768
#define K_DIM    2304
#define MG       2816     // W cols = SIZE_OUT + NUM_GATES
#define SIZE_OUT 2304
#define NGATE    512
#define NT       108      // K' = 3*2304 = 6912 k-elems / BK=64

typedef short bf16x8 __attribute__((ext_vector_type(8)));
typedef float f32x4  __attribute__((ext_vector_type(4)));

__device__ __forceinline__ short f2bf(float f) {
    unsigned u = __builtin_bit_cast(unsigned, f);
    unsigned r = u + 0x7FFFu + ((u >> 16) & 1u);   // RNE to bf16
    return (short)(r >> 16);
}
__device__ __forceinline__ float bf2f(short s) {
    unsigned u = ((unsigned)(unsigned short)s) << 16;
    return __builtin_bit_cast(float, u);
}

// ---------------------------------------------------------------------------
// Pre-pass: split x into hi/lo bf16 planes [N][K].
// ---------------------------------------------------------------------------
__global__ __launch_bounds__(256)
void split_x_k(const float* __restrict__ x, short* __restrict__ xh,
               short* __restrict__ xl) {
    const size_t total = (size_t)N_ROWS * K_DIM / 8;
    for (size_t i = (size_t)blockIdx.x * 256 + threadIdx.x; i < total;
         i += (size_t)gridDim.x * 256) {
        f32x4 v0 = *(const f32x4*)(x + i * 8);
        f32x4 v1 = *(const f32x4*)(x + i * 8 + 4);
        bf16x8 h, l;
#pragma unroll
        for (int e = 0; e < 4; ++e) {
            short hb = f2bf(v0[e]); h[e] = hb; l[e] = f2bf(v0[e] - bf2f(hb));
            short hb2 = f2bf(v1[e]); h[e+4] = hb2; l[e+4] = f2bf(v1[e] - bf2f(hb2));
        }
        *(bf16x8*)&xh[i * 8] = h;
        *(bf16x8*)&xl[i * 8] = l;
    }
}

// ---------------------------------------------------------------------------
// Pre-pass: split W (fp32 [K][MG]) into hi/lo bf16, transposed to [MG][K].
// ---------------------------------------------------------------------------
__global__ __launch_bounds__(256)
void split_w_k(const float* __restrict__ W, short* __restrict__ wh,
               short* __restrict__ wl) {
    const int kc = blockIdx.x;
    const int m  = blockIdx.y * 256 + threadIdx.x;
    bf16x8 h, l;
#pragma unroll
    for (int j = 0; j < 8; ++j) {
        float f = W[(size_t)(kc * 8 + j) * MG + m];
        short hb = f2bf(f);
        h[j] = hb;
        l[j] = f2bf(f - bf2f(hb));
    }
    *(bf16x8*)&wh[(size_t)m * K_DIM + kc * 8] = h;
    *(bf16x8*)&wl[(size_t)m * K_DIM + kc * 8] = l;
}

// ---------------------------------------------------------------------------
// K'-concat plane selectors: A' = [xh | xh | xl], B' = [wh | wl | wh]
// => terms hh + hl + lh over K'=6912, tile-aligned (36 tiles per third).
// ---------------------------------------------------------------------------
__device__ __forceinline__ const short* asel(const short* xh, const short* xl, int t) {
    return (t < 36) ? xh + t * 64 : (t < 72) ? xh + (t - 36) * 64 : xl + (t - 72) * 64;
}
__device__ __forceinline__ const short* bsel(const short* wh, const short* wl, int t) {
    return (t < 36) ? wh + t * 64 : (t < 72) ? wl + (t - 36) * 64 : wh + (t - 72) * 64;
}

#define BAR() do { asm volatile("" ::: "memory"); \
                   __builtin_amdgcn_s_barrier();  \
                   asm volatile("" ::: "memory"); } while (0)

// Stage one half-tile (128 rows x 64 k, 16 KiB) via global_load_lds dwordx4.
// LDS dest is linear; global source is pre-swizzled (slot = c16 ^ (row&7)).
#define STAGE_HALF(ldsbase, src, R0, half) do {                                \
    const short* g0_ = (src) + ((size_t)((R0) + (half) * 128 + w * 8 + l8)) * K_DIM + swz; \
    const short* g1_ = (src) + ((size_t)((R0) + (half) * 128 + 64 + w * 8 + l8)) * K_DIM + swz; \
    __builtin_amdgcn_global_load_lds(                                          \
        (const __attribute__((address_space(1))) void*)g0_,                    \
        (__attribute__((address_space(3))) void*)((ldsbase) + (half) * 8192 + w * 512), \
        16, 0, 0);                                                             \
    __builtin_amdgcn_global_load_lds(                                          \
        (const __attribute__((address_space(1))) void*)g1_,                    \
        (__attribute__((address_space(3))) void*)((ldsbase) + (half) * 8192 + 4096 + w * 512), \
        16, 0, 0);                                                             \
} while (0)

#define PHASE_MFMA(MB, KS, AFR)                                                \
    __builtin_amdgcn_s_setprio(1);                                             \
    _Pragma("unroll") for (int mm = 0; mm < 4; ++mm)                           \
    _Pragma("unroll") for (int nn = 0; nn < 4; ++nn)                           \
        acc[(MB) + mm][nn] = __builtin_amdgcn_mfma_f32_16x16x32_bf16(          \
            AFR[mm], bfr[nn][KS], acc[(MB) + mm][nn], 0, 0, 0);                \
    __builtin_amdgcn_s_setprio(0);

// ---------------------------------------------------------------------------
// 256x256 tile, BK=64, 8 waves (2Mx4N), 4 phases/tile, counted vmcnt.
// MODE 0: gate cols (W rows 2304..2815) -> sigmoid -> gates ws.
// MODE 1: field cols -> silu / gate-mul -> out.
// ---------------------------------------------------------------------------
template <int MODE, int NCT>
__global__ __launch_bounds__(512, 2)
void gemm8_k(const short* __restrict__ xh, const short* __restrict__ xl,
             const short* __restrict__ wh, const short* __restrict__ wl,
             float* __restrict__ gates, float* __restrict__ out) {
    __shared__ short lds[2][2][16384];   // [buf][A/B][32KB]

    const int tid  = threadIdx.x;
    const int lane = tid & 63;
    const int w    = tid >> 6;           // wave 0..7
    const int wm   = w >> 2;             // 0..1  (row half)
    const int wn   = w & 3;              // 0..3  (col quarter)

    // XCD-aware bijective swizzle (grid % 8 == 0 for both modes)
    const int nwg = NCT * (N_ROWS / 256);
    const int cpx = nwg >> 3;
    const int wg  = (blockIdx.x & 7) * cpx + (blockIdx.x >> 3);
    const int rowt = wg / NCT, colt = wg % NCT;
    const int row0  = rowt * 256;                         // x rows
    const int bcol0 = (MODE == 0 ? SIZE_OUT : 0) + colt * 256;  // W-plane rows

    // staging lane constants
    const int l8 = lane >> 3, l7 = lane & 7;
    const int swz = (l7 ^ l8) << 3;      // pre-swizzled slot, in shorts

    // fragment-read lane constants
    const int frow = lane & 15, hi = lane >> 4;
    const int s0 = (hi ^ (frow & 7)) << 3;   // slot*8 shorts, ks=0
    const int s1 = s0 ^ 32;                  // ks=1

    f32x4 acc[8][4] = {};
    bf16x8 bfr[4][2];

    // ---- prologue: tile0 A+B, tile1 A; leave tile1.A in flight
    {
        const short* a0 = asel(xh, xl, 0);
        const short* b0 = bsel(wh, wl, 0);
        const short* a1 = asel(xh, xl, 1);
        STAGE_HALF(lds[0][0], a0, row0, 0);  STAGE_HALF(lds[0][0], a0, row0, 1);
        STAGE_HALF(lds[0][1], b0, bcol0, 0); STAGE_HALF(lds[0][1], b0, bcol0, 1);
        STAGE_HALF(lds[1][0], a1, row0, 0);  STAGE_HALF(lds[1][0], a1, row0, 1);
    }
    asm volatile("s_waitcnt vmcnt(4)" ::: "memory");
    BAR();

    for (int t = 0; t < NT; ++t) {
        short* Ab = lds[t & 1][0];
        short* Bb = lds[t & 1][1];
        short* Bn = lds[(t + 1) & 1][1];
        const short* bsrc1 = bsel(wh, wl, t + 1);   // valid only if t+1<NT
        const short* asrc2 = asel(xh, xl, t + 2);   // valid only if t+2<NT

        bf16x8 afr0[4], afr1[4], afr2[4], afr3[4];

        // ---- P0: read A m0-3 ks0 + all B; stage t+1.B.h0
#pragma unroll
        for (int n = 0; n < 4; ++n) {
            const int col = (wn * 64 + n * 16 + frow) * 64;
            bfr[n][0] = *(const bf16x8*)&Bb[col + s0];
            bfr[n][1] = *(const bf16x8*)&Bb[col + s1];
        }
#pragma unroll
        for (int m = 0; m < 4; ++m)
            afr0[m] = *(const bf16x8*)&Ab[(wm * 128 + m * 16 + frow) * 64 + s0];
        if (t + 1 < NT) STAGE_HALF(Bn, bsrc1, bcol0, 0);
        BAR();
        PHASE_MFMA(0, 0, afr0)
        BAR();

        // ---- P1: read A m4-7 ks0, A m0-3 ks1; stage t+1.B.h1
#pragma unroll
        for (int m = 0; m < 4; ++m)
            afr1[m] = *(const bf16x8*)&Ab[(wm * 128 + 64 + m * 16 + frow) * 64 + s0];
#pragma unroll
        for (int m = 0; m < 4; ++m)
            afr2[m] = *(const bf16x8*)&Ab[(wm * 128 + m * 16 + frow) * 64 + s1];
        if (t + 1 < NT) STAGE_HALF(Bn, bsrc1, bcol0, 1);
        BAR();
        PHASE_MFMA(4, 0, afr1)
        BAR();

        // ---- P2: read A m4-7 ks1; after this phase buf is fully read
#pragma unroll
        for (int m = 0; m < 4; ++m)
            afr3[m] = *(const bf16x8*)&Ab[(wm * 128 + 64 + m * 16 + frow) * 64 + s1];
        BAR();
        PHASE_MFMA(0, 1, afr2)
        asm volatile("s_waitcnt lgkmcnt(0)" ::: "memory");  // afr3 reads done -> buf free
        BAR();

        // ---- P3: stage t+2.A into just-freed buf; counted vmcnt
        if (t + 2 < NT) {
            STAGE_HALF(Ab, asrc2, row0, 0);
            STAGE_HALF(Ab, asrc2, row0, 1);
        }
        BAR();
        PHASE_MFMA(4, 1, afr3)
        if (t < NT - 2) { asm volatile("s_waitcnt vmcnt(4)" ::: "memory"); }
        else           { asm volatile("s_waitcnt vmcnt(0)" ::: "memory"); }
        BAR();
    }

    // ---- epilogue: D col = lane&15 (B/W index), row = (lane>>4)*4+reg (A/x index)
    const int rb = row0 + wm * 128 + hi * 4;
    const int cl = wn * 64 + frow;           // local col in tile

    if (MODE == 0) {
#pragma unroll
        for (int m = 0; m < 8; ++m)
#pragma unroll
            for (int n = 0; n < 4; ++n) {
                const int c = colt * 256 + cl + n * 16;   // gate col 0..511
#pragma unroll
                for (int r = 0; r < 4; ++r) {
                    const int row = rb + m * 16 + r;
                    float v = acc[m][n][r];
                    gates[(size_t)row * NGATE + c] = 1.0f / (1.0f + __expf(-v));
                }
            }
    } else {
#pragma unroll
        for (int m = 0; m < 8; ++m)
#pragma unroll
            for (int n = 0; n < 4; ++n) {
                const int c = colt * 256 + cl + n * 16;   // out col 0..2303
                int g = 0;
                if (c >= 256) g = (c < 1024) ? (c - 256) / 3 : 256 + (c - 1024) / 5;
#pragma unroll
                for (int r = 0; r < 4; ++r) {
                    const int row = rb + m * 16 + r;
                    float v = acc[m][n][r];
                    float o;
                    if (colt == 0) o = v / (1.0f + __expf(-v));          // silu
                    else           o = v * gates[(size_t)row * NGATE + g];
                    out[(size_t)row * SIZE_OUT + c] = o;
                }
            }
    }
}

// ===========================================================================
// Fallback (round-1 verified path) if ws is too small for the x planes.
// ===========================================================================
#define BM 128
#define BN 128
#define BK 32
#define LDSK 40
typedef short s16x4 __attribute__((ext_vector_type(4)));

template <int MODE>
__global__ __launch_bounds__(256, 2)
void gemm_fb(const float* __restrict__ x, const short* __restrict__ wh,
             const short* __restrict__ wl, float* __restrict__ gates,
             float* __restrict__ out) {
    __shared__ short Ah[BM * LDSK], Al[BM * LDSK];
    __shared__ short Bh[BN * LDSK], Bl[BN * LDSK];
    const int tid = threadIdx.x, lane = tid & 63, wave = tid >> 6;
    const int wm = wave >> 1, wn = wave & 1;
    const int n0 = blockIdx.x * BN, r0 = blockIdx.y * BM;
    const int wcol0 = (MODE == 0 ? SIZE_OUT : 0) + n0;
    const int srow = tid >> 1, skh = (tid & 1) * 16;
    const float* xp  = x  + (size_t)(r0 + srow) * K_DIM + skh;
    const short* whp = wh + (size_t)(wcol0 + srow) * K_DIM + skh;
    const short* wlp = wl + (size_t)(wcol0 + srow) * K_DIM + skh;
    f32x4 acc[4][4] = {};
    const int frow = lane & 15, fk = (lane >> 4) * 8;
    for (int kt = 0; kt < K_DIM / BK; ++kt) {
        const float* ap = xp + kt * BK;
        const short* bhp = whp + kt * BK;
        const short* blp = wlp + kt * BK;
        s16x4 ah_[4], al_[4];
#pragma unroll
        for (int c = 0; c < 4; ++c) {
            f32x4 v = *(const f32x4*)(ap + c * 4);
#pragma unroll
            for (int e = 0; e < 4; ++e) {
                short hb = f2bf(v[e]);
                ah_[c][e] = hb;
                al_[c][e] = f2bf(v[e] - bf2f(hb));
            }
        }
        bf16x8 bh0 = *(const bf16x8*)(bhp);
        bf16x8 bh1 = *(const bf16x8*)(bhp + 8);
        bf16x8 bl0 = *(const bf16x8*)(blp);
        bf16x8 bl1 = *(const bf16x8*)(blp + 8);
        __syncthreads();
#pragma unroll
        for (int c = 0; c < 4; ++c) {
            *(s16x4*)&Ah[srow * LDSK + skh + c * 4] = ah_[c];
            *(s16x4*)&Al[srow * LDSK + skh + c * 4] = al_[c];
        }
        *(bf16x8*)&Bh[srow * LDSK + skh] = bh0;
        *(bf16x8*)&Bh[srow * LDSK + skh + 8] = bh1;
        *(bf16x8*)&Bl[srow * LDSK + skh] = bl0;
        *(bf16x8*)&Bl[srow * LDSK + skh + 8] = bl1;
        __syncthreads();
        bf16x8 a_h[4], a_l[4], b_h[4], b_l[4];
#pragma unroll
        for (int i = 0; i < 4; ++i) {
            const int ar = (wm * 64 + i * 16 + frow) * LDSK + fk;
            a_h[i] = *(const bf16x8*)&Ah[ar];
            a_l[i] = *(const bf16x8*)&Al[ar];
            const int br = (wn * 64 + i * 16 + frow) * LDSK + fk;
            b_h[i] = *(const bf16x8*)&Bh[br];
            b_l[i] = *(const bf16x8*)&Bl[br];
        }
#pragma unroll
        for (int i = 0; i < 4; ++i)
#pragma unroll
            for (int j = 0; j < 4; ++j) {
                acc[i][j] = __builtin_amdgcn_mfma_f32_16x16x32_bf16(a_h[i], b_h[j], acc[i][j], 0, 0, 0);
                acc[i][j] = __builtin_amdgcn_mfma_f32_16x16x32_bf16(a_h[i], b_l[j], acc[i][j], 0, 0, 0);
                acc[i][j] = __builtin_amdgcn_mfma_f32_16x16x32_bf16(a_l[i], b_h[j], acc[i][j], 0, 0, 0);
            }
    }
    const int rb = r0 + wm * 64 + ((lane >> 4) << 2);
    const int cb = n0 + wn * 64 + (lane & 15);
    if (MODE == 0) {
#pragma unroll
        for (int i = 0; i < 4; ++i)
#pragma unroll
            for (int j = 0; j < 4; ++j) {
                const int c = cb + j * 16;
#pragma unroll
                for (int r = 0; r < 4; ++r)
                    gates[(size_t)(rb + i * 16 + r) * NGATE + c] =
                        1.0f / (1.0f + __expf(-acc[i][j][r]));
            }
    } else {
#pragma unroll
        for (int i = 0; i < 4; ++i)
#pragma unroll
            for (int j = 0; j < 4; ++j) {
                const int c = cb + j * 16;
                int g = 0;
                if (n0 >= 256) g = (n0 < 1024) ? (c - 256) / 3 : 256 + (c - 1024) / 5;
#pragma unroll
                for (int r = 0; r < 4; ++r) {
                    const int row = rb + i * 16 + r;
                    float v = acc[i][j][r];
                    float o = (n0 < 256) ? v / (1.0f + __expf(-v))
                                         : v * gates[(size_t)row * NGATE + g];
                    out[(size_t)row * SIZE_OUT + c] = o;
                }
            }
    }
}

// ---------------------------------------------------------------------------
extern "C" void kernel_launch(void* const* d_in, const int* in_sizes, int n_in,
                              void* d_out, int out_size, void* d_ws,
                              size_t ws_size, hipStream_t stream) {
    const float* x = (const float*)d_in[0];
    const float* W = (const float*)d_in[1];
    float* out = (float*)d_out;
    char* ws = (char*)d_ws;

    const size_t xplane = (size_t)N_ROWS * K_DIM * 2;   // 151.0 MB
    const size_t wplane = (size_t)MG * K_DIM * 2;       // 13.0 MB
    const size_t gbytes = (size_t)N_ROWS * NGATE * 4;   // 67.1 MB

    if (ws_size >= 2 * xplane + 2 * wplane + gbytes) {
        short* xh = (short*)ws;
        short* xl = (short*)(ws + xplane);
        short* wh = (short*)(ws + 2 * xplane);
        short* wl = (short*)(ws + 2 * xplane + wplane);
        float* gates = (float*)(ws + 2 * xplane + 2 * wplane);

        split_x_k<<<2048, 256, 0, stream>>>(x, xh, xl);
        split_w_k<<<dim3(K_DIM / 8, MG / 256), 256, 0, stream>>>(W, wh, wl);
        gemm8_k<0, NGATE / 256><<<(NGATE / 256) * (N_ROWS / 256), 512, 0, stream>>>(
            xh, xl, wh, wl, gates, out);
        gemm8_k<1, SIZE_OUT / 256><<<(SIZE_OUT / 256) * (N_ROWS / 256), 512, 0, stream>>>(
            xh, xl, wh, wl, gates, out);
    } else if (ws_size >= 2 * wplane + gbytes) {
        short* wh = (short*)ws;
        short* wl = (short*)(ws + wplane);
        float* gates = (float*)(ws + 2 * wplane);
        split_w_k<<<dim3(K_DIM / 8, MG / 256), 256, 0, stream>>>(W, wh, wl);
        gemm_fb<0><<<dim3(NGATE / BN, N_ROWS / BM), 256, 0, stream>>>(x, wh, wl, gates, out);
        gemm_fb<1><<<dim3(SIZE_OUT / BN, N_ROWS / BM), 256, 0, stream>>>(x, wh, wl, gates, out);
    }
}

// Round 3
// 1431.055 us; speedup vs baseline: 1.4335x; 1.2259x over previous
//
#include <hip/hip_runtime.h>

// Problem constants
#define N_ROWS   32768
#define K_DIM    2304
#define MG       2816     // W cols = SIZE_OUT + NUM_GATES
#define SIZE_OUT 2304
#define NGATE    512
#define NT       72       // K' = 2*2304 = 4608 k-elems / BK=64

typedef short bf16x8 __attribute__((ext_vector_type(8)));
typedef float f32x4  __attribute__((ext_vector_type(4)));

__device__ __forceinline__ short f2bf(float f) {
    unsigned u = __builtin_bit_cast(unsigned, f);
    unsigned r = u + 0x7FFFu + ((u >> 16) & 1u);   // RNE to bf16
    return (short)(r >> 16);
}
__device__ __forceinline__ float bf2f(short s) {
    unsigned u = ((unsigned)(unsigned short)s) << 16;
    return __builtin_bit_cast(float, u);
}

// ---------------------------------------------------------------------------
// Pre-pass: split x into hi/lo bf16 planes [N][K] (double-bf16 of x).
// ---------------------------------------------------------------------------
__global__ __launch_bounds__(256)
void split_x_k(const float* __restrict__ x, short* __restrict__ xh,
               short* __restrict__ xl) {
    const size_t total = (size_t)N_ROWS * K_DIM / 8;
    for (size_t i = (size_t)blockIdx.x * 256 + threadIdx.x; i < total;
         i += (size_t)gridDim.x * 256) {
        f32x4 v0 = *(const f32x4*)(x + i * 8);
        f32x4 v1 = *(const f32x4*)(x + i * 8 + 4);
        bf16x8 h, l;
#pragma unroll
        for (int e = 0; e < 4; ++e) {
            short hb = f2bf(v0[e]); h[e] = hb; l[e] = f2bf(v0[e] - bf2f(hb));
            short hb2 = f2bf(v1[e]); h[e+4] = hb2; l[e+4] = f2bf(v1[e] - bf2f(hb2));
        }
        *(bf16x8*)&xh[i * 8] = h;
        *(bf16x8*)&xl[i * 8] = l;
    }
}

// ---------------------------------------------------------------------------
// Pre-pass: W (fp32 [K][MG]) -> bf16, transposed to [MG][K].
// ---------------------------------------------------------------------------
__global__ __launch_bounds__(256)
void split_w_k(const float* __restrict__ W, short* __restrict__ wt) {
    const int kc = blockIdx.x;
    const int m  = blockIdx.y * 256 + threadIdx.x;
    bf16x8 h;
#pragma unroll
    for (int j = 0; j < 8; ++j)
        h[j] = f2bf(W[(size_t)(kc * 8 + j) * MG + m]);
    *(bf16x8*)&wt[(size_t)m * K_DIM + kc * 8] = h;
}

// ---------------------------------------------------------------------------
// K'-concat plane selectors: A' = [xh | xl], B' = [wt | wt]  (K' = 4608)
// ---------------------------------------------------------------------------
__device__ __forceinline__ const short* asel(const short* xh, const short* xl, int t) {
    return (t < 36) ? xh + t * 64 : xl + (t - 36) * 64;
}
__device__ __forceinline__ const short* bsel(const short* wt, int t) {
    return (t < 36) ? wt + t * 64 : wt + (t - 36) * 64;
}

#define BAR() do { asm volatile("" ::: "memory"); \
                   __builtin_amdgcn_s_barrier();  \
                   asm volatile("" ::: "memory"); } while (0)

// Stage one half-tile (128 rows x 64 k, 16 KiB) via global_load_lds dwordx4.
// LDS dest linear; global source pre-swizzled (slot = chunk ^ (row&7)).
#define STAGE_HALF(ldsbase, src, R0, half) do {                                \
    const short* g0_ = (src) + ((size_t)((R0) + (half) * 128 + w * 8 + l8)) * K_DIM + swz; \
    const short* g1_ = (src) + ((size_t)((R0) + (half) * 128 + 64 + w * 8 + l8)) * K_DIM + swz; \
    __builtin_amdgcn_global_load_lds(                                          \
        (const __attribute__((address_space(1))) void*)g0_,                    \
        (__attribute__((address_space(3))) void*)((ldsbase) + (half) * 8192 + w * 512), \
        16, 0, 0);                                                             \
    __builtin_amdgcn_global_load_lds(                                          \
        (const __attribute__((address_space(1))) void*)g1_,                    \
        (__attribute__((address_space(3))) void*)((ldsbase) + (half) * 8192 + 4096 + w * 512), \
        16, 0, 0);                                                             \
} while (0)

#define PHASE_MFMA(MB, KS, AFR)                                                \
    __builtin_amdgcn_s_setprio(1);                                             \
    _Pragma("unroll") for (int mm = 0; mm < 4; ++mm)                           \
    _Pragma("unroll") for (int nn = 0; nn < 4; ++nn)                           \
        acc[(MB) + mm][nn] = __builtin_amdgcn_mfma_f32_16x16x32_bf16(          \
            AFR[mm], bfr[nn][KS], acc[(MB) + mm][nn], 0, 0, 0);                \
    __builtin_amdgcn_s_setprio(0);

// ---------------------------------------------------------------------------
// 256x256 tile, BK=64, 8 waves (2Mx4N), 4 phases/tile, balanced reads
// (8/4/8/4), 1 half-tile staged per phase, counted vmcnt(2) once per tile.
// MODE 0: gate cols (W rows 2304..2815) -> sigmoid -> gates ws.
// MODE 1: field cols -> silu / gate-mul -> out.
// ---------------------------------------------------------------------------
template <int MODE, int NCT>
__global__ __launch_bounds__(512, 2)
void gemm8_k(const short* __restrict__ xh, const short* __restrict__ xl,
             const short* __restrict__ wt,
             float* __restrict__ gates, float* __restrict__ out) {
    __shared__ short lds[2][2][16384];   // [buf][A/B][32KB]

    const int tid  = threadIdx.x;
    const int lane = tid & 63;
    const int w    = tid >> 6;           // wave 0..7
    const int wm   = w >> 2;             // 0..1  (row half)
    const int wn   = w & 3;              // 0..3  (col quarter)

    // XCD-aware bijective swizzle (grid % 8 == 0 for both modes)
    const int nwg = NCT * (N_ROWS / 256);
    const int cpx = nwg >> 3;
    const int wg  = (blockIdx.x & 7) * cpx + (blockIdx.x >> 3);
    const int rowt = wg / NCT, colt = wg % NCT;
    const int row0  = rowt * 256;                               // x rows
    const int bcol0 = (MODE == 0 ? SIZE_OUT : 0) + colt * 256;  // W-plane rows

    // staging lane constants
    const int l8 = lane >> 3, l7 = lane & 7;
    const int swz = (l7 ^ l8) << 3;          // pre-swizzled chunk, in shorts

    // fragment-read lane constants
    const int frow = lane & 15, hi = lane >> 4;
    const int s0 = (hi ^ (frow & 7)) << 3;   // slot*8 shorts, ks=0
    const int s1 = s0 ^ 32;                  // ks=1 (chunk hi^4)

    f32x4 acc[8][4] = {};
    bf16x8 bfr[4][2];

    // ---- prologue: tile0 fully + tile1 A.h0; drain tile0 (vmcnt(2))
    {
        const short* a0 = asel(xh, xl, 0);
        const short* b0 = bsel(wt, 0);
        const short* a1 = asel(xh, xl, 1);
        STAGE_HALF(lds[0][0], a0, row0, 0);  STAGE_HALF(lds[0][0], a0, row0, 1);
        STAGE_HALF(lds[0][1], b0, bcol0, 0); STAGE_HALF(lds[0][1], b0, bcol0, 1);
        STAGE_HALF(lds[1][0], a1, row0, 0);
    }
    asm volatile("s_waitcnt vmcnt(2)" ::: "memory");
    BAR();

#pragma unroll 1
    for (int t = 0; t < NT; ++t) {
        short* Ab = lds[t & 1][0];
        short* Bb = lds[t & 1][1];
        short* An = lds[(t + 1) & 1][0];
        short* Bn = lds[(t + 1) & 1][1];
        const int t1 = (t + 1 < NT) ? t + 1 : NT - 1;
        const int t2 = (t + 2 < NT) ? t + 2 : NT - 1;
        const short* asrc1 = asel(xh, xl, t1);
        const short* bsrc1 = bsel(wt, t1);
        const short* asrc2 = asel(xh, xl, t2);

        bf16x8 afr0[4], afr1[4], afr2[4], afr3[4];

        // ---- P0: read B ks0 + A(m0-3,ks0); stage A(t+1).h1
#pragma unroll
        for (int n = 0; n < 4; ++n)
            bfr[n][0] = *(const bf16x8*)&Bb[(wn * 64 + n * 16 + frow) * 64 + s0];
#pragma unroll
        for (int m = 0; m < 4; ++m)
            afr0[m] = *(const bf16x8*)&Ab[(wm * 128 + m * 16 + frow) * 64 + s0];
        if (t + 1 < NT) STAGE_HALF(An, asrc1, row0, 1);
        BAR();
        PHASE_MFMA(0, 0, afr0)
        BAR();

        // ---- P1: read A(m4-7,ks0); stage B(t+1).h0
#pragma unroll
        for (int m = 0; m < 4; ++m)
            afr1[m] = *(const bf16x8*)&Ab[(wm * 128 + 64 + m * 16 + frow) * 64 + s0];
        if (t + 1 < NT) STAGE_HALF(Bn, bsrc1, bcol0, 0);
        BAR();
        PHASE_MFMA(4, 0, afr1)
        BAR();

        // ---- P2: read B ks1 + A(m0-3,ks1); stage B(t+1).h1
#pragma unroll
        for (int n = 0; n < 4; ++n)
            bfr[n][1] = *(const bf16x8*)&Bb[(wn * 64 + n * 16 + frow) * 64 + s1];
#pragma unroll
        for (int m = 0; m < 4; ++m)
            afr2[m] = *(const bf16x8*)&Ab[(wm * 128 + m * 16 + frow) * 64 + s1];
        if (t + 1 < NT) STAGE_HALF(Bn, bsrc1, bcol0, 1);
        BAR();
        PHASE_MFMA(0, 1, afr2)
        BAR();

        // ---- P3: read A(m4-7,ks1); WAR-free the buf, then stage A(t+2).h0
#pragma unroll
        for (int m = 0; m < 4; ++m)
            afr3[m] = *(const bf16x8*)&Ab[(wm * 128 + 64 + m * 16 + frow) * 64 + s1];
        asm volatile("s_waitcnt lgkmcnt(0)" ::: "memory");  // all my reads done
        BAR();                                              // => all waves' reads done
        if (t + 2 < NT) STAGE_HALF(Ab, asrc2, row0, 0);
        PHASE_MFMA(4, 1, afr3)
        if (t + 2 < NT) { asm volatile("s_waitcnt vmcnt(2)" ::: "memory"); }
        else            { asm volatile("s_waitcnt vmcnt(0)" ::: "memory"); }
        BAR();
    }

    // ---- epilogue: D col = lane&15 (W index), row = (lane>>4)*4+reg (x index)
    const int rb = row0 + wm * 128 + hi * 4;
    const int cl = wn * 64 + frow;           // local col in tile

    if (MODE == 0) {
#pragma unroll
        for (int m = 0; m < 8; ++m)
#pragma unroll
            for (int n = 0; n < 4; ++n) {
                const int c = colt * 256 + cl + n * 16;   // gate col 0..511
#pragma unroll
                for (int r = 0; r < 4; ++r) {
                    const int row = rb + m * 16 + r;
                    float v = acc[m][n][r];
                    gates[(size_t)row * NGATE + c] = 1.0f / (1.0f + __expf(-v));
                }
            }
    } else {
#pragma unroll
        for (int m = 0; m < 8; ++m)
#pragma unroll
            for (int n = 0; n < 4; ++n) {
                const int c = colt * 256 + cl + n * 16;   // out col 0..2303
                int g = 0;
                if (c >= 256) g = (c < 1024) ? (c - 256) / 3 : 256 + (c - 1024) / 5;
#pragma unroll
                for (int r = 0; r < 4; ++r) {
                    const int row = rb + m * 16 + r;
                    float v = acc[m][n][r];
                    float o;
                    if (colt == 0) o = v / (1.0f + __expf(-v));          // silu
                    else           o = v * gates[(size_t)row * NGATE + g];
                    out[(size_t)row * SIZE_OUT + c] = o;
                }
            }
    }
}

// ---------------------------------------------------------------------------
extern "C" void kernel_launch(void* const* d_in, const int* in_sizes, int n_in,
                              void* d_out, int out_size, void* d_ws,
                              size_t ws_size, hipStream_t stream) {
    const float* x = (const float*)d_in[0];
    const float* W = (const float*)d_in[1];
    float* out = (float*)d_out;
    char* ws = (char*)d_ws;

    const size_t xplane = (size_t)N_ROWS * K_DIM * 2;   // 151.0 MB
    const size_t wplane = (size_t)MG * K_DIM * 2;       // 13.0 MB
    const size_t gbytes = (size_t)N_ROWS * NGATE * 4;   // 67.1 MB
    const size_t needed = 2 * xplane + wplane + gbytes; // ~382 MB

    if (ws_size < needed) return;  // fail loudly (output stays poisoned)

    short* xh    = (short*)ws;
    short* xl    = (short*)(ws + xplane);
    short* wt    = (short*)(ws + 2 * xplane);
    float* gates = (float*)(ws + 2 * xplane + wplane);

    split_x_k<<<2048, 256, 0, stream>>>(x, xh, xl);
    split_w_k<<<dim3(K_DIM / 8, MG / 256), 256, 0, stream>>>(W, wt);
    gemm8_k<0, NGATE / 256><<<(NGATE / 256) * (N_ROWS / 256), 512, 0, stream>>>(
        xh, xl, wt, gates, out);
    gemm8_k<1, SIZE_OUT / 256><<<(SIZE_OUT / 256) * (N_ROWS / 256), 512, 0, stream>>>(
        xh, xl, wt, gates, out);
}